// Round 2
// baseline (351.828 us; speedup 1.0000x reference)
//
#include <hip/hip_runtime.h>
#include <hip/hip_bf16.h>

// Problem constants (from reference): B=512, T=64, A=32, H=512, E=32
#define B_ 512
#define T_ 64
#define A_ 32
#define H_ 512
#define E_ 32
#define MAX_TASKS 272   // sum_e ceil(cnt_e/2) <= 256/2 + 32 slack

typedef unsigned short u16;
typedef unsigned int u32;
typedef __attribute__((ext_vector_type(8))) short short8;   // 8 bf16 = 4 VGPRs (MFMA A/B frag)
typedef __attribute__((ext_vector_type(4))) float floatx4;  // MFMA C/D frag

static __device__ __forceinline__ u16 f2bf(float f) {
    u32 u = __builtin_bit_cast(u32, f);
    u += 0x7fffu + ((u >> 16) & 1u);   // RNE
    return (u16)(u >> 16);
}

// ---------------------------------------------------------------------------
// Kernel 1: group samples by expert (counting sort) + build M-block task list.
// One block, 512 threads. tasks[i] = {expert, slot0, nsamp (0/1/2), pad}.
// Task-build parallelized across 32 threads (one per expert).
// ---------------------------------------------------------------------------
__global__ void group_kernel(const int* __restrict__ cat_ids,
                             int* __restrict__ sample_list,
                             int4* __restrict__ tasks) {
    __shared__ int cnt[E_], off[E_], cur[E_], toff[E_];
    __shared__ int total;
    int tid = threadIdx.x;
    if (tid < E_) { cnt[tid] = 0; cur[tid] = 0; }
    __syncthreads();
    int e = cat_ids[tid];               // tid in [0,512) == B_
    atomicAdd(&cnt[e], 1);
    __syncthreads();
    if (tid == 0) {
        int run = 0, trun = 0;
        for (int i = 0; i < E_; i++) {
            off[i] = run;  run += cnt[i];
            toff[i] = trun; trun += (cnt[i] + 1) >> 1;
        }
        total = trun;
    }
    __syncthreads();
    if (tid < E_) {
        int c = cnt[tid], o = off[tid], to = toff[tid];
        for (int j = 0; j < c; j += 2)
            tasks[to++] = make_int4(tid, o + j, (c - j >= 2) ? 2 : 1, 0);
    }
    for (int i = total + tid; i < MAX_TASKS; i += 512)
        tasks[i] = make_int4(0, 0, 0, 0);
    int p = atomicAdd(&cur[e], 1);
    sample_list[off[e] + p] = tid;
}

// ---------------------------------------------------------------------------
// Kernel 2: per-sample tau embedding (512-vec, shared across T) + GEMM1
// a_emb = actions @ W1[e] + b1[e]  (fp32 VALU, K=32), stored bf16.
// ---------------------------------------------------------------------------
__global__ __launch_bounds__(256) void embed_kernel(
        const float* __restrict__ actions, const float* __restrict__ timesteps,
        const int* __restrict__ cat_ids, const float* __restrict__ W1,
        const float* __restrict__ b1, u16* __restrict__ a_emb,
        u16* __restrict__ tau_emb) {
    int b = blockIdx.x;
    int tid = threadIdx.x;
    int e = cat_ids[b];
    float tval = timesteps[b];

    // tau: freqs = exp(-ln(10000)*i/256), i in [0,256); [sin | cos]
    {
        float freq = expf(-9.210340371976184f * (float)tid * (1.0f / 256.0f));
        float ang = tval * freq;
        tau_emb[b * H_ + tid]       = f2bf(sinf(ang));
        tau_emb[b * H_ + 256 + tid] = f2bf(cosf(ang));
    }

    __shared__ float act[T_ * A_];
    const float* asrc = actions + (size_t)b * T_ * A_;
    for (int i = tid; i < T_ * A_; i += 256) act[i] = asrc[i];
    __syncthreads();

    const float* w1 = W1 + (size_t)e * A_ * H_;
    int n0 = tid, n1 = tid + 256;
    float wA[A_], wB[A_];
#pragma unroll
    for (int k = 0; k < A_; k++) {
        wA[k] = w1[k * H_ + n0];
        wB[k] = w1[k * H_ + n1];
    }
    float bA = b1[e * H_ + n0], bB = b1[e * H_ + n1];
    u16* orow = a_emb + (size_t)b * T_ * H_;
    for (int tt = 0; tt < T_; tt++) {
        float accA = bA, accB = bB;
#pragma unroll
        for (int k = 0; k < A_; k++) {
            float a = act[tt * A_ + k];   // LDS broadcast
            accA = fmaf(a, wA[k], accA);
            accB = fmaf(a, wB[k], accB);
        }
        orow[tt * H_ + n0] = f2bf(accA);
        orow[tt * H_ + n1] = f2bf(accB);
    }
}

// ---------------------------------------------------------------------------
// Kernel 3: W [E][K][512] f32  ->  Wt [E][512][K] bf16  (convert + transpose)
// grid (K/32, 2, E), block 256. Lane = n (coalesced dword reads per k-slice);
// each lane writes a full 64B line of its own n-row (write-coalesced at line
// granularity). No LDS -> no transpose bank conflicts.
// ---------------------------------------------------------------------------
__global__ __launch_bounds__(256) void convert_transpose(
        const float* __restrict__ W, u16* __restrict__ Wt, int K) {
    int n = blockIdx.y * 256 + threadIdx.x;
    int k0 = blockIdx.x * 32;
    int e = blockIdx.z;
    const float* src = W + ((size_t)e * K + k0) * H_ + n;
    short8 out[4];
#pragma unroll
    for (int j = 0; j < 32; j++)
        out[j >> 3][j & 7] = (short)f2bf(src[(size_t)j * H_]);
    u16* dst = Wt + ((size_t)e * H_ + n) * K + k0;
#pragma unroll
    for (int c = 0; c < 4; c++) *(short8*)(dst + c * 8) = out[c];
}

// ---------------------------------------------------------------------------
// Kernels 4/5: expert-grouped MFMA GEMM. Block tile M=128 (2 samples), N=128,
// BK=64. 2x2 wave grid: each wave owns a 64x64 sub-tile (4x4 MFMA tiles,
// A-frag and B-frag each reused 4x from LDS). Both tiles staged as bf16 b128
// loads; stride 72 el (144B) -> frag reads 2-way bank aliased (free, m136),
// staging writes bank-uniform. W comes pre-transposed bf16 [e][n][k].
// GEMM2 (DIN=1024): K in [512,1024) rows come from per-sample tau (broadcast
// over T).
// ---------------------------------------------------------------------------
#define LDSTR 72

template <int DIN, bool HAS_TAU, bool DO_SWISH, bool OUT_BF16>
__global__ __launch_bounds__(256, 3) void moe_gemm(
        const u16* __restrict__ xsrc, const u16* __restrict__ tau,
        const u16* __restrict__ Wt, const float* __restrict__ bias,
        const int* __restrict__ sample_list, const int4* __restrict__ tasks,
        void* __restrict__ outp) {
    int4 task = tasks[blockIdx.y];
    int ns = task.z;
    if (ns == 0) return;
    int e = task.x;
    int s0 = sample_list[task.y];
    int s1 = (ns > 1) ? sample_list[task.y + 1] : s0;  // dup reads, masked store
    int n0 = blockIdx.x * 128;

    int tid = threadIdx.x;
    int lane = tid & 63, wv = tid >> 6;
    int wr = wv >> 1, wc = wv & 1;          // 2x2 wave grid
    int quad = lane >> 4, c15 = lane & 15;

    __shared__ __align__(16) u16 xs[128 * LDSTR];  // [row][k] k=0..63
    __shared__ __align__(16) u16 wt[128 * LDSTR];  // [n][k]

    floatx4 acc[4][4];
    floatx4 zero4 = {0.f, 0.f, 0.f, 0.f};
#pragma unroll
    for (int i = 0; i < 4; i++)
#pragma unroll
        for (int j = 0; j < 4; j++) acc[i][j] = zero4;

    const u16* wbase = Wt + (size_t)(e * H_ + n0) * DIN;
    int sr = tid >> 2;          // 0..63 (staging row)
    int sk = (tid & 3) * 16;    // k offset 0/16/32/48

    for (int k0 = 0; k0 < DIN; k0 += 64) {
        bool use_tau = HAS_TAU && (k0 >= 512);
        // ---- stage x tile (128 rows x 64 k): 2 rows x 32B per thread ----
#pragma unroll
        for (int h = 0; h < 2; h++) {
            int row = sr + h * 64;
            int s = (row < 64) ? s0 : s1;
            int t = row & 63;
            const u16* src = use_tau
                ? (tau + (size_t)s * H_ + (k0 - 512) + sk)
                : (xsrc + ((size_t)s * T_ + t) * H_ + k0 + sk);
            *(short8*)&xs[row * LDSTR + sk]     = *(const short8*)src;
            *(short8*)&xs[row * LDSTR + sk + 8] = *(const short8*)(src + 8);
        }
        // ---- stage W tile (128 n x 64 k) from pre-transposed bf16 ----
#pragma unroll
        for (int h = 0; h < 2; h++) {
            int nn = sr + h * 64;
            const u16* src = wbase + (size_t)nn * DIN + k0 + sk;
            *(short8*)&wt[nn * LDSTR + sk]     = *(const short8*)src;
            *(short8*)&wt[nn * LDSTR + sk + 8] = *(const short8*)(src + 8);
        }
        __syncthreads();

#pragma unroll
        for (int kk = 0; kk < 2; kk++) {
            short8 af[4], bfr[4];
#pragma unroll
            for (int i = 0; i < 4; i++) {
                af[i]  = *(const short8*)&xs[(wr * 64 + i * 16 + c15) * LDSTR + kk * 32 + quad * 8];
                bfr[i] = *(const short8*)&wt[(wc * 64 + i * 16 + c15) * LDSTR + kk * 32 + quad * 8];
            }
#pragma unroll
            for (int mt = 0; mt < 4; mt++)
#pragma unroll
                for (int nt = 0; nt < 4; nt++)
                    acc[mt][nt] = __builtin_amdgcn_mfma_f32_16x16x32_bf16(
                            af[mt], bfr[nt], acc[mt][nt], 0, 0, 0);
        }
        __syncthreads();
    }

    // ---- epilogue: C/D layout col=c15, row=quad*4+r ----
    const float* bp = bias + (size_t)e * H_;
#pragma unroll
    for (int mt = 0; mt < 4; mt++) {
        int rbase = wr * 64 + mt * 16 + quad * 4;
        int side = rbase >> 6;            // 0: sample s0 rows, 1: s1 rows
        if (side == 1 && ns == 1) continue;
        int s = side ? s1 : s0;
#pragma unroll
        for (int nt = 0; nt < 4; nt++) {
            int col = n0 + wc * 64 + nt * 16 + c15;
            float bv = bp[col];
#pragma unroll
            for (int r = 0; r < 4; r++) {
                int t = (rbase + r) & 63;
                float v = acc[mt][nt][r] + bv;
                if (DO_SWISH) v = v / (1.0f + expf(-v));   // x*sigmoid(x)
                size_t oidx = ((size_t)s * T_ + t) * H_ + col;
                if (OUT_BF16) ((u16*)outp)[oidx] = f2bf(v);
                else          ((float*)outp)[oidx] = v;
            }
        }
    }
}

// ---------------------------------------------------------------------------
extern "C" void kernel_launch(void* const* d_in, const int* in_sizes, int n_in,
                              void* d_out, int out_size, void* d_ws, size_t ws_size,
                              hipStream_t stream) {
    const float* actions   = (const float*)d_in[0];
    const float* timesteps = (const float*)d_in[1];
    const int*   cat_ids   = (const int*)d_in[2];
    const float* W1 = (const float*)d_in[3];
    const float* b1 = (const float*)d_in[4];
    const float* W2 = (const float*)d_in[5];
    const float* b2 = (const float*)d_in[6];
    const float* W3 = (const float*)d_in[7];
    const float* b3 = (const float*)d_in[8];

    // ws layout: a_emb 32MB (reused as Wt3 after GEMM2) | y 32MB | tau 512KB
    //            | sample_list | tasks.  Wt2 (33.5MB) lives in d_out (67MB),
    //            which is pure scratch until GEMM3's epilogue overwrites it.
    char* ws = (char*)d_ws;
    u16* a_emb = (u16*)ws;                                        // 512*64*512 bf16
    u16* y     = (u16*)(ws + (size_t)32 * 1024 * 1024);           // 512*64*512 bf16
    u16* tau   = (u16*)(ws + (size_t)64 * 1024 * 1024);           // 512*512 bf16
    int* sample_list = (int*)(ws + (size_t)64 * 1024 * 1024 + 512 * 1024);
    int4* tasks = (int4*)(ws + (size_t)64 * 1024 * 1024 + 512 * 1024 + 4096);
    u16* Wt2 = (u16*)d_out;        // 32*512*1024 bf16 = 33.5MB, scratch phase
    u16* Wt3 = a_emb;              // overwrites a_emb after GEMM2 consumed it

    hipLaunchKernelGGL(group_kernel, dim3(1), dim3(512), 0, stream,
                       cat_ids, sample_list, tasks);
    hipLaunchKernelGGL(embed_kernel, dim3(512), dim3(256), 0, stream,
                       actions, timesteps, cat_ids, W1, b1, a_emb, tau);
    hipLaunchKernelGGL(convert_transpose, dim3(2 * H_ / 32, 2, E_), dim3(256),
                       0, stream, W2, Wt2, 2 * H_);
    hipLaunchKernelGGL((moe_gemm<2 * H_, true, true, true>), dim3(4, MAX_TASKS),
                       dim3(256), 0, stream,
                       a_emb, tau, Wt2, b2, sample_list, tasks, (void*)y);
    hipLaunchKernelGGL(convert_transpose, dim3(H_ / 32, 2, E_), dim3(256),
                       0, stream, W3, Wt3, H_);
    hipLaunchKernelGGL((moe_gemm<H_, false, false, false>), dim3(4, MAX_TASKS),
                       dim3(256), 0, stream,
                       y, (const u16*)nullptr, Wt3, b3, sample_list, tasks, d_out);
}

// Round 3
// 322.986 us; speedup vs baseline: 1.0893x; 1.0893x over previous
//
#include <hip/hip_runtime.h>
#include <hip/hip_bf16.h>

// Problem constants (from reference): B=512, T=64, A=32, H=512, E=32
#define B_ 512
#define T_ 64
#define A_ 32
#define H_ 512
#define E_ 32
#define MAX_TASKS 160   // sum_e ceil(cnt_e/4) <= 512/4 + 32*3/4 = 152

typedef unsigned short u16;
typedef unsigned int u32;
typedef __attribute__((ext_vector_type(8))) short short8;   // 8 bf16 (MFMA A/B frag)
typedef __attribute__((ext_vector_type(4))) float floatx4;  // MFMA C/D frag

static __device__ __forceinline__ u16 f2bf(float f) {
    u32 u = __builtin_bit_cast(u32, f);
    u += 0x7fffu + ((u >> 16) & 1u);   // RNE
    return (u16)(u >> 16);
}

// async global->LDS, 16B per lane; LDS dest must be wave-uniform base (HW does
// base + lane*16). Swizzle is applied on the GLOBAL address per lane.
static __device__ __forceinline__ void gl2lds16(const u16* g, u16* l) {
    __builtin_amdgcn_global_load_lds(
        (const __attribute__((address_space(1))) void*)g,
        (__attribute__((address_space(3))) void*)l, 16, 0, 0);
}

// ---------------------------------------------------------------------------
// Kernel 1: group samples by expert + build 4-sample task list.
// tasks[i] = {expert, slot0, nsamp (1..4), 0}.
// ---------------------------------------------------------------------------
__global__ void group_kernel(const int* __restrict__ cat_ids,
                             int* __restrict__ sample_list,
                             int4* __restrict__ tasks) {
    __shared__ int cnt[E_], off[E_], cur[E_], toff[E_];
    __shared__ int total;
    int tid = threadIdx.x;
    if (tid < E_) { cnt[tid] = 0; cur[tid] = 0; }
    __syncthreads();
    int e = cat_ids[tid];               // tid in [0,512) == B_
    atomicAdd(&cnt[e], 1);
    __syncthreads();
    if (tid == 0) {
        int run = 0, trun = 0;
        for (int i = 0; i < E_; i++) {
            off[i] = run;  run += cnt[i];
            toff[i] = trun; trun += (cnt[i] + 3) >> 2;
        }
        total = trun;
    }
    __syncthreads();
    if (tid < E_) {
        int c = cnt[tid], o = off[tid], to = toff[tid];
        for (int j = 0; j < c; j += 4) {
            int ns = c - j; if (ns > 4) ns = 4;
            tasks[to++] = make_int4(tid, o + j, ns, 0);
        }
    }
    for (int i = total + tid; i < MAX_TASKS; i += 512)
        tasks[i] = make_int4(0, 0, 0, 0);
    int p = atomicAdd(&cur[e], 1);
    sample_list[off[e] + p] = tid;
}

// ---------------------------------------------------------------------------
// Kernel 2: per-sample tau embedding + GEMM1 (K=32, fp32 VALU) -> bf16.
// ---------------------------------------------------------------------------
__global__ __launch_bounds__(256) void embed_kernel(
        const float* __restrict__ actions, const float* __restrict__ timesteps,
        const int* __restrict__ cat_ids, const float* __restrict__ W1,
        const float* __restrict__ b1, u16* __restrict__ a_emb,
        u16* __restrict__ tau_emb) {
    int b = blockIdx.x;
    int tid = threadIdx.x;
    int e = cat_ids[b];
    float tval = timesteps[b];

    {
        float freq = expf(-9.210340371976184f * (float)tid * (1.0f / 256.0f));
        float ang = tval * freq;
        tau_emb[b * H_ + tid]       = f2bf(sinf(ang));
        tau_emb[b * H_ + 256 + tid] = f2bf(cosf(ang));
    }

    __shared__ float act[T_ * A_];
    const float* asrc = actions + (size_t)b * T_ * A_;
    for (int i = tid; i < T_ * A_; i += 256) act[i] = asrc[i];
    __syncthreads();

    const float* w1 = W1 + (size_t)e * A_ * H_;
    int n0 = tid, n1 = tid + 256;
    float wA[A_], wB[A_];
#pragma unroll
    for (int k = 0; k < A_; k++) {
        wA[k] = w1[k * H_ + n0];
        wB[k] = w1[k * H_ + n1];
    }
    float bA = b1[e * H_ + n0], bB = b1[e * H_ + n1];
    u16* orow = a_emb + (size_t)b * T_ * H_;
    for (int tt = 0; tt < T_; tt++) {
        float accA = bA, accB = bB;
#pragma unroll
        for (int k = 0; k < A_; k++) {
            float a = act[tt * A_ + k];   // LDS broadcast
            accA = fmaf(a, wA[k], accA);
            accB = fmaf(a, wB[k], accB);
        }
        orow[tt * H_ + n0] = f2bf(accA);
        orow[tt * H_ + n1] = f2bf(accB);
    }
}

// ---------------------------------------------------------------------------
// Kernel 3: W [E][K][512] f32 -> Wt [E][512][K] bf16 (convert + transpose).
// ---------------------------------------------------------------------------
__global__ __launch_bounds__(256) void convert_transpose(
        const float* __restrict__ W, u16* __restrict__ Wt, int K) {
    int n = blockIdx.y * 256 + threadIdx.x;
    int k0 = blockIdx.x * 32;
    int e = blockIdx.z;
    const float* src = W + ((size_t)e * K + k0) * H_ + n;
    short8 out[4];
#pragma unroll
    for (int j = 0; j < 32; j++)
        out[j >> 3][j & 7] = (short)f2bf(src[(size_t)j * H_]);
    u16* dst = Wt + ((size_t)e * H_ + n) * K + k0;
#pragma unroll
    for (int c = 0; c < 4; c++) *(short8*)(dst + c * 8) = out[c];
}

// ---------------------------------------------------------------------------
// Kernels 4/5: expert-grouped MFMA GEMM.
// Block: 512 threads (8 waves), tile M=256 (4 samples) x N=128, BK=64.
// Wave grid 4x2 -> each wave owns a 64x64 sub-tile (4x4 MFMA tiles; A and B
// frags each reused 4x). Staging via global_load_lds (16B/lane, async, no
// VGPR round-trip, conflict-free LDS writes). LDS layout: row-major stride 64
// with XOR swizzle: chunk c (16B) of row r lives at slot (c ^ (r&7)) -> frag
// reads are 2-way bank aliased (free). Swizzle applied on the global address
// side of global_load_lds (its LDS side is fixed base + lane*16).
// GEMM2 (DIN=1024): K in [512,1024) comes from per-sample tau (bcast over T).
// ---------------------------------------------------------------------------
template <int DIN, bool HAS_TAU, bool DO_SWISH, bool OUT_BF16>
__global__ __launch_bounds__(512, 4) void moe_gemm(
        const u16* __restrict__ xsrc, const u16* __restrict__ tau,
        const u16* __restrict__ Wt, const float* __restrict__ bias,
        const int* __restrict__ sample_list, const int4* __restrict__ tasks,
        void* __restrict__ outp) {
    int4 task = tasks[blockIdx.y];
    int ns = task.z;
    if (ns == 0) return;
    int e = task.x;
    int sl[4];
#pragma unroll
    for (int j = 0; j < 4; j++)
        sl[j] = sample_list[task.y + ((j < ns) ? j : (ns - 1))];
    int n0 = blockIdx.x * 128;

    int tid = threadIdx.x;
    int lane = tid & 63, wv = tid >> 6;          // 8 waves
    int wr = wv >> 1, wc = wv & 1;               // 4x2 wave grid
    int quad = lane >> 4, c15 = lane & 15;
    int r8 = lane >> 3, cg = lane & 7;           // staging: row-in-group, chunk slot

    __shared__ __align__(16) u16 xs[256 * 64];   // 32 KB
    __shared__ __align__(16) u16 wt[128 * 64];   // 16 KB

    floatx4 acc[4][4];
    floatx4 zero4 = {0.f, 0.f, 0.f, 0.f};
#pragma unroll
    for (int i = 0; i < 4; i++)
#pragma unroll
        for (int j = 0; j < 4; j++) acc[i][j] = zero4;

    const u16* wbase = Wt + (size_t)(e * H_ + n0) * DIN;
    int kc_sw = (cg ^ r8) * 8;                   // swizzled global k-offset (elems)

    for (int k0 = 0; k0 < DIN; k0 += 64) {
        bool use_tau = HAS_TAU && (k0 >= 512);
        // ---- stage x tile: 32 wave-instrs total, 4 per wave (j = sample) ----
#pragma unroll
        for (int j = 0; j < 4; j++) {
            int rg = 8 * wv + 64 * j;            // wave-uniform row-group base
            int t = 8 * wv + r8;                 // t = row & 63
            int s = sl[j];
            const u16* g = use_tau
                ? (tau + (size_t)s * H_ + (k0 - 512) + kc_sw)
                : (xsrc + ((size_t)s * T_ + t) * H_ + k0 + kc_sw);
            gl2lds16(g, &xs[rg * 64]);
        }
        // ---- stage W tile: 16 wave-instrs total, 2 per wave ----
#pragma unroll
        for (int i = 0; i < 2; i++) {
            int ng = 8 * wv + 64 * i;            // wave-uniform n-group base
            int nrow = ng + r8;
            const u16* g = wbase + (size_t)nrow * DIN + k0 + kc_sw;
            gl2lds16(g, &wt[ng * 64]);
        }
        __syncthreads();   // drains vmcnt (global_load_lds) before frag reads

#pragma unroll
        for (int kk = 0; kk < 2; kk++) {
            int c = kk * 4 + quad;               // k-chunk index 0..7
            short8 af[4], bfr[4];
#pragma unroll
            for (int i = 0; i < 4; i++) {
                int row = wr * 64 + i * 16 + c15;
                af[i] = *(const short8*)&xs[row * 64 + ((c ^ (row & 7)) * 8)];
                int nr = wc * 64 + i * 16 + c15;
                bfr[i] = *(const short8*)&wt[nr * 64 + ((c ^ (nr & 7)) * 8)];
            }
#pragma unroll
            for (int mt = 0; mt < 4; mt++)
#pragma unroll
                for (int nt = 0; nt < 4; nt++)
                    acc[mt][nt] = __builtin_amdgcn_mfma_f32_16x16x32_bf16(
                            af[mt], bfr[nt], acc[mt][nt], 0, 0, 0);
        }
        __syncthreads();
    }

    // ---- epilogue: C/D layout col=c15, row=quad*4+r; wave wr = sample wr ----
    if (wr >= ns) return;
    int s = sl[wr];
    const float* bp = bias + (size_t)e * H_;
#pragma unroll
    for (int mt = 0; mt < 4; mt++) {
        int tb = mt * 16 + quad * 4;             // t base within sample
#pragma unroll
        for (int nt = 0; nt < 4; nt++) {
            int col = n0 + wc * 64 + nt * 16 + c15;
            float bv = bp[col];
#pragma unroll
            for (int r = 0; r < 4; r++) {
                float v = acc[mt][nt][r] + bv;
                if (DO_SWISH) v = v / (1.0f + expf(-v));   // x*sigmoid(x)
                size_t oidx = ((size_t)s * T_ + tb + r) * H_ + col;
                if (OUT_BF16) ((u16*)outp)[oidx] = f2bf(v);
                else          ((float*)outp)[oidx] = v;
            }
        }
    }
}

// ---------------------------------------------------------------------------
extern "C" void kernel_launch(void* const* d_in, const int* in_sizes, int n_in,
                              void* d_out, int out_size, void* d_ws, size_t ws_size,
                              hipStream_t stream) {
    const float* actions   = (const float*)d_in[0];
    const float* timesteps = (const float*)d_in[1];
    const int*   cat_ids   = (const int*)d_in[2];
    const float* W1 = (const float*)d_in[3];
    const float* b1 = (const float*)d_in[4];
    const float* W2 = (const float*)d_in[5];
    const float* b2 = (const float*)d_in[6];
    const float* W3 = (const float*)d_in[7];
    const float* b3 = (const float*)d_in[8];

    // ws: a_emb 32MB (reused as Wt3 after GEMM2) | y 32MB | tau 512KB | lists.
    // Wt2 (33.5MB) lives in d_out (67MB) — scratch until GEMM3's epilogue.
    char* ws = (char*)d_ws;
    u16* a_emb = (u16*)ws;
    u16* y     = (u16*)(ws + (size_t)32 * 1024 * 1024);
    u16* tau   = (u16*)(ws + (size_t)64 * 1024 * 1024);
    int* sample_list = (int*)(ws + (size_t)64 * 1024 * 1024 + 512 * 1024);
    int4* tasks = (int4*)(ws + (size_t)64 * 1024 * 1024 + 512 * 1024 + 4096);
    u16* Wt2 = (u16*)d_out;
    u16* Wt3 = a_emb;

    hipLaunchKernelGGL(group_kernel, dim3(1), dim3(512), 0, stream,
                       cat_ids, sample_list, tasks);
    hipLaunchKernelGGL(embed_kernel, dim3(512), dim3(256), 0, stream,
                       actions, timesteps, cat_ids, W1, b1, a_emb, tau);
    hipLaunchKernelGGL(convert_transpose, dim3(2 * H_ / 32, 2, E_), dim3(256),
                       0, stream, W2, Wt2, 2 * H_);
    hipLaunchKernelGGL((moe_gemm<2 * H_, true, true, true>), dim3(4, MAX_TASKS),
                       dim3(512), 0, stream,
                       a_emb, tau, Wt2, b2, sample_list, tasks, (void*)y);
    hipLaunchKernelGGL(convert_transpose, dim3(H_ / 32, 2, E_), dim3(256),
                       0, stream, W3, Wt3, H_);
    hipLaunchKernelGGL((moe_gemm<H_, false, false, false>), dim3(4, MAX_TASKS),
                       dim3(512), 0, stream,
                       y, (const u16*)nullptr, Wt3, b3, sample_list, tasks, d_out);
}

// Round 4
// 315.795 us; speedup vs baseline: 1.1141x; 1.0228x over previous
//
#include <hip/hip_runtime.h>
#include <hip/hip_bf16.h>

// Problem constants (from reference): B=512, T=64, A=32, H=512, E=32
#define B_ 512
#define T_ 64
#define A_ 32
#define H_ 512
#define E_ 32
#define MAX_TASKS 272   // sum_e ceil(cnt_e/2) <= 256 + 16
#define CAP_ 168        // itemlist capacity per XCD class
#define GRID_ (8 * CAP_)

typedef unsigned short u16;
typedef unsigned int u32;
typedef __attribute__((ext_vector_type(8))) short short8;   // 8 bf16 (MFMA A/B frag)
typedef __attribute__((ext_vector_type(4))) float floatx4;  // MFMA C/D frag

static __device__ __forceinline__ u16 f2bf(float f) {
    u32 u = __builtin_bit_cast(u32, f);
    u += 0x7fffu + ((u >> 16) & 1u);   // RNE
    return (u16)(u >> 16);
}

// async global->LDS, 16B per lane; LDS dest is wave-uniform base (HW adds
// lane*16). Swizzle must be applied on the GLOBAL address per lane.
static __device__ __forceinline__ void gl2lds16(const u16* g, u16* l) {
    __builtin_amdgcn_global_load_lds(
        (const __attribute__((address_space(1))) void*)g,
        (__attribute__((address_space(3))) void*)l, 16, 0, 0);
}

// ---------------------------------------------------------------------------
// Kernel 1: group samples by expert, build 2-sample tasks, and build the
// XCD-affinity item list: slot f runs on XCD f%8 (round-robin dispatch
// heuristic); all items of expert e are placed on XCD e%8, task-major, so a
// task's 4 N-blocks are temporally adjacent on one XCD (x-tile L2 reuse) and
// same-expert tasks share W stripes in that L2. Skew overflow -> sequential
// fallback (perf-only degradation).
// itemlist[f] = (task<<2)|nb, or -1 (dead block).
// ---------------------------------------------------------------------------
__global__ void group_kernel(const int* __restrict__ cat_ids,
                             int* __restrict__ sample_list,
                             int4* __restrict__ tasks,
                             int* __restrict__ itemlist) {
    __shared__ int cnt[E_], off[E_], cur[E_], toff[E_], jc[8];
    __shared__ int total, fb;
    int tid = threadIdx.x;
    if (tid < E_) { cnt[tid] = 0; cur[tid] = 0; }
    __syncthreads();
    int e = cat_ids[tid];               // tid in [0,512) == B_
    atomicAdd(&cnt[e], 1);
    __syncthreads();
    if (tid == 0) {
        int run = 0, trun = 0;
        for (int i = 0; i < E_; i++) {
            off[i] = run;  run += cnt[i];
            toff[i] = trun; trun += (cnt[i] + 1) >> 1;
        }
        total = trun;
    }
    __syncthreads();
    if (tid < E_) {
        int c = cnt[tid], o = off[tid], to = toff[tid];
        for (int j = 0; j < c; j += 2)
            tasks[to++] = make_int4(tid, o + j, (c - j >= 2) ? 2 : 1, 0);
    }
    if (tid < 8) {
        int J = 0;
        for (int cc = 0; cc < 4; cc++) J += 4 * ((cnt[tid + 8 * cc] + 1) >> 1);
        jc[tid] = J;
    }
    __syncthreads();
    if (tid == 0) {
        int f = 0;
        for (int x = 0; x < 8; x++) if (jc[x] > CAP_) f = 1;
        fb = f;
    }
    __syncthreads();
    if (!fb) {
        if (tid < 8) {
            int j = 0;
            for (int cc = 0; cc < 4; cc++) {
                int ee = tid + 8 * cc;
                int nt = (cnt[ee] + 1) >> 1, t0 = toff[ee];
                for (int t = t0; t < t0 + nt; t++)
                    for (int nb = 0; nb < 4; nb++) {
                        itemlist[tid + 8 * j] = (t << 2) | nb;
                        j++;
                    }
            }
            for (; j < CAP_; j++) itemlist[tid + 8 * j] = -1;
        }
    } else {
        for (int f = tid; f < GRID_; f += 512)
            itemlist[f] = (f < 4 * total) ? f : -1;
    }
    int p = atomicAdd(&cur[e], 1);
    sample_list[off[e] + p] = tid;
}

// ---------------------------------------------------------------------------
// Kernel 2: per-sample tau embedding + GEMM1 (K=32, fp32 VALU) -> bf16.
// ---------------------------------------------------------------------------
__global__ __launch_bounds__(256) void embed_kernel(
        const float* __restrict__ actions, const float* __restrict__ timesteps,
        const int* __restrict__ cat_ids, const float* __restrict__ W1,
        const float* __restrict__ b1, u16* __restrict__ a_emb,
        u16* __restrict__ tau_emb) {
    int b = blockIdx.x;
    int tid = threadIdx.x;
    int e = cat_ids[b];
    float tval = timesteps[b];

    {
        float freq = expf(-9.210340371976184f * (float)tid * (1.0f / 256.0f));
        float ang = tval * freq;
        tau_emb[b * H_ + tid]       = f2bf(sinf(ang));
        tau_emb[b * H_ + 256 + tid] = f2bf(cosf(ang));
    }

    __shared__ float act[T_ * A_];
    const float* asrc = actions + (size_t)b * T_ * A_;
    for (int i = tid; i < T_ * A_; i += 256) act[i] = asrc[i];
    __syncthreads();

    const float* w1 = W1 + (size_t)e * A_ * H_;
    int n0 = tid, n1 = tid + 256;
    float wA[A_], wB[A_];
#pragma unroll
    for (int k = 0; k < A_; k++) {
        wA[k] = w1[k * H_ + n0];
        wB[k] = w1[k * H_ + n1];
    }
    float bA = b1[e * H_ + n0], bB = b1[e * H_ + n1];
    u16* orow = a_emb + (size_t)b * T_ * H_;
    for (int tt = 0; tt < T_; tt++) {
        float accA = bA, accB = bB;
#pragma unroll
        for (int k = 0; k < A_; k++) {
            float a = act[tt * A_ + k];   // LDS broadcast
            accA = fmaf(a, wA[k], accA);
            accB = fmaf(a, wB[k], accB);
        }
        orow[tt * H_ + n0] = f2bf(accA);
        orow[tt * H_ + n1] = f2bf(accB);
    }
}

// ---------------------------------------------------------------------------
// Kernel 3: W [E][K][512] f32 -> Wt [E][512][K] bf16 (convert + transpose).
// ---------------------------------------------------------------------------
__global__ __launch_bounds__(256) void convert_transpose(
        const float* __restrict__ W, u16* __restrict__ Wt, int K) {
    int n = blockIdx.y * 256 + threadIdx.x;
    int k0 = blockIdx.x * 32;
    int e = blockIdx.z;
    const float* src = W + ((size_t)e * K + k0) * H_ + n;
    short8 out[4];
#pragma unroll
    for (int j = 0; j < 32; j++)
        out[j >> 3][j & 7] = (short)f2bf(src[(size_t)j * H_]);
    u16* dst = Wt + ((size_t)e * H_ + n) * K + k0;
#pragma unroll
    for (int c = 0; c < 4; c++) *(short8*)(dst + c * 8) = out[c];
}

// ---------------------------------------------------------------------------
// Kernels 4/5: expert-grouped MFMA GEMM, m97-style tile.
// Block: 256 threads (4 waves), tile M=128 (2 samples) x N=128, BK=64.
// Wave grid 2x2 -> each wave 64x64 (4x4 MFMA tiles, 64 acc AGPRs).
// Staging via global_load_lds 16B/lane (async, no VGPR round-trip, conflict-
// free LDS writes). LDS: row-major stride 64 elems, XOR swizzle: 16B chunk c
// of row r at slot c^(r&7) (applied on the global address side) -> frag reads
// 2-way aliased (free). 32 KB LDS -> ~4 blocks/CU for inter-block overlap.
// Work item from XCD-affinity itemlist (x/W re-reads become same-XCD L2 hits).
// GEMM2 (DIN=1024): K in [512,1024) comes from per-sample tau (bcast over T).
// ---------------------------------------------------------------------------
template <int DIN, bool HAS_TAU, bool DO_SWISH, bool OUT_BF16>
__global__ __launch_bounds__(256, 4) void moe_gemm(
        const u16* __restrict__ xsrc, const u16* __restrict__ tau,
        const u16* __restrict__ Wt, const float* __restrict__ bias,
        const int* __restrict__ sample_list, const int4* __restrict__ tasks,
        const int* __restrict__ itemlist, void* __restrict__ outp) {
    int item = itemlist[blockIdx.x];
    if (item < 0) return;
    int4 task = tasks[item >> 2];
    int nb = item & 3;
    int ns = task.z;
    int e = task.x;
    int s0 = sample_list[task.y];
    int s1 = (ns > 1) ? sample_list[task.y + 1] : s0;  // dup reads, masked store
    int n0 = nb * 128;

    int tid = threadIdx.x;
    int lane = tid & 63, wv = tid >> 6;          // 4 waves
    int wr = wv >> 1, wc = wv & 1;               // 2x2 wave grid
    int quad = lane >> 4, c15 = lane & 15;
    int r8 = lane >> 3, cg = lane & 7;           // staging: row-in-group, chunk

    __shared__ __align__(16) u16 xs[128 * 64];   // 16 KB
    __shared__ __align__(16) u16 wt[128 * 64];   // 16 KB

    floatx4 acc[4][4];
    floatx4 zero4 = {0.f, 0.f, 0.f, 0.f};
#pragma unroll
    for (int i = 0; i < 4; i++)
#pragma unroll
        for (int j = 0; j < 4; j++) acc[i][j] = zero4;

    const u16* wbase = Wt + (size_t)(e * H_ + n0) * DIN;
    int kc_sw = (cg ^ r8) * 8;                   // swizzled global k-offset

    for (int k0 = 0; k0 < DIN; k0 += 64) {
        bool use_tau = HAS_TAU && (k0 >= 512);
        // ---- stage x tile (128 rows x 64 k): 4 wave-instrs per wave ----
#pragma unroll
        for (int h = 0; h < 4; h++) {
            int rbase = h * 32 + wv * 8;         // wave-uniform row-group base
            int row = rbase + r8;
            int s = (rbase < 64) ? s0 : s1;
            int t = row & 63;
            const u16* g = use_tau
                ? (tau + (size_t)s * H_ + (k0 - 512) + kc_sw)
                : (xsrc + ((size_t)s * T_ + t) * H_ + k0 + kc_sw);
            gl2lds16(g, &xs[rbase * 64]);
        }
        // ---- stage W tile (128 n x 64 k): 4 wave-instrs per wave ----
#pragma unroll
        for (int h = 0; h < 4; h++) {
            int nbase = h * 32 + wv * 8;
            int nrow = nbase + r8;
            gl2lds16(wbase + (size_t)nrow * DIN + k0 + kc_sw, &wt[nbase * 64]);
        }
        __syncthreads();   // drains vmcnt before frag reads

#pragma unroll
        for (int kk = 0; kk < 2; kk++) {
            int c = kk * 4 + quad;               // k-chunk index 0..7
            short8 af[4], bfr[4];
#pragma unroll
            for (int i = 0; i < 4; i++) {
                int row = wr * 64 + i * 16 + c15;
                af[i] = *(const short8*)&xs[row * 64 + ((c ^ (row & 7)) * 8)];
                int nr = wc * 64 + i * 16 + c15;
                bfr[i] = *(const short8*)&wt[nr * 64 + ((c ^ (nr & 7)) * 8)];
            }
#pragma unroll
            for (int mt = 0; mt < 4; mt++)
#pragma unroll
                for (int nt = 0; nt < 4; nt++)
                    acc[mt][nt] = __builtin_amdgcn_mfma_f32_16x16x32_bf16(
                            af[mt], bfr[nt], acc[mt][nt], 0, 0, 0);
        }
        __syncthreads();
    }

    // ---- epilogue: C/D layout col=c15, row=quad*4+r; wave-row wr = sample ----
    if (wr >= ns) return;
    int s = (wr == 0) ? s0 : s1;
    const float* bp = bias + (size_t)e * H_;
#pragma unroll
    for (int mt = 0; mt < 4; mt++) {
        int tb = mt * 16 + quad * 4;             // t base within sample
#pragma unroll
        for (int nt = 0; nt < 4; nt++) {
            int col = n0 + wc * 64 + nt * 16 + c15;
            float bv = bp[col];
#pragma unroll
            for (int r = 0; r < 4; r++) {
                float v = acc[mt][nt][r] + bv;
                if (DO_SWISH) v = v / (1.0f + expf(-v));   // x*sigmoid(x)
                size_t oidx = ((size_t)s * T_ + tb + r) * H_ + col;
                if (OUT_BF16) ((u16*)outp)[oidx] = f2bf(v);
                else          ((float*)outp)[oidx] = v;
            }
        }
    }
}

// ---------------------------------------------------------------------------
extern "C" void kernel_launch(void* const* d_in, const int* in_sizes, int n_in,
                              void* d_out, int out_size, void* d_ws, size_t ws_size,
                              hipStream_t stream) {
    const float* actions   = (const float*)d_in[0];
    const float* timesteps = (const float*)d_in[1];
    const int*   cat_ids   = (const int*)d_in[2];
    const float* W1 = (const float*)d_in[3];
    const float* b1 = (const float*)d_in[4];
    const float* W2 = (const float*)d_in[5];
    const float* b2 = (const float*)d_in[6];
    const float* W3 = (const float*)d_in[7];
    const float* b3 = (const float*)d_in[8];

    // ws: a_emb 32MB (reused as Wt3 after GEMM2) | y 32MB | tau 512KB | lists.
    // Wt2 (33.5MB) lives in d_out (67MB) — scratch until GEMM3's epilogue.
    char* ws = (char*)d_ws;
    u16* a_emb = (u16*)ws;
    u16* y     = (u16*)(ws + (size_t)32 * 1024 * 1024);
    u16* tau   = (u16*)(ws + (size_t)64 * 1024 * 1024);
    char* meta = ws + (size_t)64 * 1024 * 1024 + 512 * 1024;
    int*  sample_list = (int*)meta;                     // 2 KB
    int4* tasks       = (int4*)(meta + 8192);           // 272*16 B
    int*  itemlist    = (int*)(meta + 16384);           // GRID_*4 B
    u16* Wt2 = (u16*)d_out;
    u16* Wt3 = a_emb;

    hipLaunchKernelGGL(group_kernel, dim3(1), dim3(512), 0, stream,
                       cat_ids, sample_list, tasks, itemlist);
    hipLaunchKernelGGL(embed_kernel, dim3(512), dim3(256), 0, stream,
                       actions, timesteps, cat_ids, W1, b1, a_emb, tau);
    hipLaunchKernelGGL(convert_transpose, dim3(2 * H_ / 32, 2, E_), dim3(256),
                       0, stream, W2, Wt2, 2 * H_);
    hipLaunchKernelGGL((moe_gemm<2 * H_, true, true, true>), dim3(GRID_),
                       dim3(256), 0, stream,
                       a_emb, tau, Wt2, b2, sample_list, tasks, itemlist, (void*)y);
    hipLaunchKernelGGL(convert_transpose, dim3(H_ / 32, 2, E_), dim3(256),
                       0, stream, W3, Wt3, H_);
    hipLaunchKernelGGL((moe_gemm<H_, false, false, false>), dim3(GRID_),
                       dim3(256), 0, stream,
                       y, (const u16*)nullptr, Wt3, b3, sample_list, tasks,
                       itemlist, d_out);
}